// Round 16
// baseline (1176.943 us; speedup 1.0000x reference)
//
#include <hip/hip_runtime.h>
#include <math.h>

#define B_ 4
#define S_ 2048
#define D_ 1024
#define F_ 4096
#define E_ 8
#define T_ 8192
#define LBW_ 0.01f
#define HROWS_ 17408   // sum of per-expert 128-padded counts <= 16384 + 8*127
#define NTILE_MAX 72   // max total 256-row M-tiles across experts

#define BUFB1 24576    // gemm1 LDS buffer: A 256x32x2 (16384) + B 128x32x2 (8192)

typedef unsigned short u16;
typedef __attribute__((ext_vector_type(8))) short bf16x8;
typedef __attribute__((ext_vector_type(4))) float f32x4;

#define GLOAD16(gp, lp) __builtin_amdgcn_global_load_lds( \
    (const __attribute__((address_space(1))) void*)(gp),  \
    (__attribute__((address_space(3))) void*)(lp), 16, 0, 0)

__device__ __forceinline__ u16 f2b(float f) {
    unsigned u = __float_as_uint(f);
    u = (u + 0x7FFFu + ((u >> 16) & 1u)) >> 16;   // RNE f32 -> bf16
    return (u16)u;
}
__device__ __forceinline__ float gelu_f(float v) {
    return 0.5f * v * (1.0f + erff(v * 0.70710678118654752440f));
}

// ------- per-expert transpose + convert: src (R x C f32) -> dst (C x R bf16) [r11 form] -------
__global__ __launch_bounds__(256) void cvt_T_kernel(const float* __restrict__ src,
                                                    u16* __restrict__ dst, int R, int C) {
    __shared__ u16 t[64][72];
    const int e = blockIdx.z;
    const float* s = src + (size_t)e * R * C;
    u16* d = dst + (size_t)e * R * C;
    const int r0 = blockIdx.y * 64, c0 = blockIdx.x * 64;
    const int tid = threadIdx.x;
    {
        int rr = tid >> 2, cq = (tid & 3) * 16;
        #pragma unroll
        for (int j = 0; j < 16; j += 4) {
            float4 v = *(const float4*)(s + (size_t)(r0 + rr) * C + c0 + cq + j);
            t[cq + j + 0][rr] = f2b(v.x);
            t[cq + j + 1][rr] = f2b(v.y);
            t[cq + j + 2][rr] = f2b(v.z);
            t[cq + j + 3][rr] = f2b(v.w);
        }
    }
    __syncthreads();
    {
        int cr = tid >> 2, rq = (tid & 3) * 16;
        #pragma unroll
        for (int j = 0; j < 16; j += 8) {
            int4 pk; u16* pw = (u16*)&pk;
            #pragma unroll
            for (int jj = 0; jj < 8; ++jj) pw[jj] = t[cr][rq + j + jj];
            *(int4*)(d + (size_t)(c0 + cr) * R + r0 + rq + j) = pk;
        }
    }
}

// ------- gate [r11 form]: f64 logits, softmax, top-2, lists, loss partials; x->bf16 -------
__global__ __launch_bounds__(64) void gate_kernel(
    const float* __restrict__ x, const float* __restrict__ ew,
    const float* __restrict__ gw, const float* __restrict__ gb,
    u16* __restrict__ xb,
    float* __restrict__ combine, int* __restrict__ idx, int* __restrict__ cnt,
    int* __restrict__ fcnt, float* __restrict__ psum)
{
    const int t = blockIdx.x, l = threadIdx.x;
    const float* xr = x + (size_t)t * D_;
    double acc[E_];
    #pragma unroll
    for (int e = 0; e < E_; ++e) acc[e] = 0.0;
    u16 xw[16];
    #pragma unroll
    for (int kk = 0; kk < 16; kk += 4) {
        float4 xv = *(const float4*)(xr + l * 16 + kk);
        float xs[4] = {xv.x, xv.y, xv.z, xv.w};
        #pragma unroll
        for (int j = 0; j < 4; ++j) {
            xw[kk + j] = f2b(xs[j]);
            const float* gr = gw + (size_t)(l * 16 + kk + j) * E_;
            float4 g0 = *(const float4*)(gr);
            float4 g1 = *(const float4*)(gr + 4);
            acc[0] += (double)xs[j] * g0.x;  acc[1] += (double)xs[j] * g0.y;
            acc[2] += (double)xs[j] * g0.z;  acc[3] += (double)xs[j] * g0.w;
            acc[4] += (double)xs[j] * g1.x;  acc[5] += (double)xs[j] * g1.y;
            acc[6] += (double)xs[j] * g1.z;  acc[7] += (double)xs[j] * g1.w;
        }
    }
    *(int4*)(xb + (size_t)t * D_ + l * 16)     = *(int4*)(xw);
    *(int4*)(xb + (size_t)t * D_ + l * 16 + 8) = *(int4*)(xw + 8);
    #pragma unroll
    for (int e = 0; e < E_; ++e) {
        #pragma unroll
        for (int m = 32; m > 0; m >>= 1) acc[e] += __shfl_xor(acc[e], m);
    }
    if (l == 0) {
        const int b = t / S_;
        double p[E_]; double mx = -1e300;
        #pragma unroll
        for (int e = 0; e < E_; ++e) {
            p[e] = acc[e] + (double)gb[e] + (double)ew[b * E_ + e];
            mx = fmax(mx, p[e]);
        }
        double s = 0.0;
        #pragma unroll
        for (int e = 0; e < E_; ++e) { p[e] = exp(p[e] - mx); s += p[e]; }
        double inv = 1.0 / s;
        #pragma unroll
        for (int e = 0; e < E_; ++e) p[e] *= inv;
        double m1 = -1.0; int e1 = 0;
        #pragma unroll
        for (int e = 0; e < E_; ++e) if (p[e] > m1) { m1 = p[e]; e1 = e; }
        double m2 = -1.0; int e2 = 0;
        #pragma unroll
        for (int e = 0; e < E_; ++e) if (e != e1 && p[e] > m2) { m2 = p[e]; e2 = e; }
        float c1 = (float)(m1 / (m1 + m2)), c2 = (float)(m2 / (m1 + m2));
        #pragma unroll
        for (int e = 0; e < E_; ++e)
            combine[t * E_ + e] = (e == e1) ? c1 : ((e == e2) ? c2 : 0.0f);
        int q1 = atomicAdd(&cnt[e1], 1); idx[e1 * T_ + q1] = t;
        int q2 = atomicAdd(&cnt[e2], 1); idx[e2 * T_ + q2] = t;
        atomicAdd(&fcnt[(t & 63) * E_ + e1], 1);
        #pragma unroll
        for (int e = 0; e < E_; ++e) atomicAdd(&psum[(t & 63) * E_ + e], (float)p[e]);
    }
}

// ------- offsets + tile table + loss (merged) -------
__global__ void tiletab_kernel(const int* __restrict__ cnt, int* __restrict__ off,
                               int* __restrict__ table, int* __restrict__ ntab,
                               const int* __restrict__ fcnt, const float* __restrict__ psum,
                               float* __restrict__ lossdst) {
    if (threadIdx.x == 0 && blockIdx.x == 0) {
        int o = 0, k = 0;
        for (int e = 0; e < E_; ++e) {
            off[e] = o;
            int pad = ((cnt[e] + 127) >> 7) << 7;
            o += pad;
            int nt = (pad + 255) >> 8;
            for (int i = 0; i < nt; ++i) table[k++] = e | (i << 4);
        }
        off[E_] = o;
        *ntab = k;
        float loss = 0.f;
        for (int e = 0; e < E_; ++e) {
            float fs = 0.f, Ps = 0.f;
            for (int s = 0; s < 64; ++s) { fs += (float)fcnt[s * E_ + e]; Ps += psum[s * E_ + e]; }
            loss += (fs / (float)T_) * (Ps / (float)T_);
        }
        *lossdst = LBW_ * (float)E_ * loss;
    }
}

// ---- GEMM1: r11's 256x128 BK32 3-buffer lead-2 vmcnt(3), 2 blocks/CU, gather INLINED ----
__global__ __launch_bounds__(512, 4) void moe_g1_kernel(
    const u16* __restrict__ xb, const u16* __restrict__ Wt,
    const float* __restrict__ bias,
    const int* __restrict__ idxAll, const int* __restrict__ cntAll,
    const int* __restrict__ off, const int* __restrict__ table,
    const int* __restrict__ ntab, u16* __restrict__ hOut)
{
    const int gid = blockIdx.x;
    const int ti = gid % NTILE_MAX;
    const int tn = gid / NTILE_MAX;
    if (ti >= *ntab) return;
    const int ent = table[ti];
    const int e = ent & 15, tm = ent >> 4;
    const int cnt = cntAll[e], base = off[e];
    const int* idx_e = idxAll + e * T_;
    const u16* Bsrc = Wt + (size_t)e * ((size_t)D_ * F_);

    __shared__ __align__(16) char lds[3 * BUFB1];   // 72KB -> 2 blocks/CU

    const int tid = threadIdx.x;
    const int l = tid & 63, wid = tid >> 6;
    const int wm = (wid >> 1) * 64, wn = (wid & 1) * 64;
    const int lr = l & 15, lg = l >> 4;

    const int qsrc = ((l & 3) ^ ((l >> 3) & 3)) * 8;
    const u16* aP[2]; const u16* bP;
    #pragma unroll
    for (int i = 0; i < 2; ++i) {
        int c = 2 * wid + i;
        int r = tm * 256 + c * 16 + (l >> 2);
        int tok = (r < cnt) ? idx_e[r] : idx_e[0];   // inline gather (r3 pattern)
        aP[i] = xb + (size_t)tok * D_ + qsrc;
    }
    {
        int cc = tn * 128 + wid * 16 + (l >> 2);
        bP = Bsrc + (size_t)cc * D_ + qsrc;
    }

    f32x4 acc[4][4];
    #pragma unroll
    for (int mi = 0; mi < 4; ++mi)
        #pragma unroll
        for (int ni = 0; ni < 4; ++ni) acc[mi][ni] = (f32x4){0.f,0.f,0.f,0.f};

    auto stage = [&](int sb, int kof) {
        GLOAD16(aP[0] + kof, lds + sb + (2 * wid) * 1024);
        GLOAD16(aP[1] + kof, lds + sb + (2 * wid + 1) * 1024);
        GLOAD16(bP + kof, lds + sb + 16384 + wid * 1024);
    };

    stage(0, 0);
    stage(BUFB1, 32);
    asm volatile("s_waitcnt vmcnt(3)" ::: "memory");
    __builtin_amdgcn_s_barrier();

    const int koff = ((((lr >> 1) & 3) ^ lg) << 4);
    int cb = 0, sb2 = 2 * BUFB1, kofe = 64;
    constexpr int NT = 32;   // K = 1024
    for (int t = 0; t < NT; ++t) {
        bf16x8 a[4], b[4];
        #pragma unroll
        for (int mi = 0; mi < 4; ++mi)
            a[mi] = *(const bf16x8*)(lds + cb + (wm + mi * 16 + lr) * 64 + koff);
        #pragma unroll
        for (int ni = 0; ni < 4; ++ni)
            b[ni] = *(const bf16x8*)(lds + cb + 16384 + (wn + ni * 16 + lr) * 64 + koff);
        if (t < NT - 2) { stage(sb2, kofe); kofe += 32; }
        __builtin_amdgcn_s_setprio(1);
        #pragma unroll
        for (int mi = 0; mi < 4; ++mi)
            #pragma unroll
            for (int ni = 0; ni < 4; ++ni)
                acc[mi][ni] = __builtin_amdgcn_mfma_f32_16x16x32_bf16(a[mi], b[ni], acc[mi][ni], 0, 0, 0);
        __builtin_amdgcn_s_setprio(0);
        if (t < NT - 2)       { asm volatile("s_waitcnt vmcnt(3)" ::: "memory"); }
        else if (t == NT - 2) { asm volatile("s_waitcnt vmcnt(0)" ::: "memory"); }
        if (t < NT - 1) __builtin_amdgcn_s_barrier();
        cb += BUFB1;  if (cb == 3 * BUFB1)  cb = 0;
        sb2 += BUFB1; if (sb2 == 3 * BUFB1) sb2 = 0;
    }

    const float* be = bias + e * F_;
    const int pad = ((cnt + 127) >> 7) << 7;
    #pragma unroll
    for (int mi = 0; mi < 4; ++mi) {
        #pragma unroll
        for (int j = 0; j < 4; ++j) {
            int rl = tm * 256 + wm + mi * 16 + lg * 4 + j;
            if (rl < pad) {
                size_t srow = (size_t)(base + rl) * F_;
                #pragma unroll
                for (int ni = 0; ni < 4; ++ni) {
                    int f = tn * 128 + wn + ni * 16 + lr;
                    hOut[srow + f] = f2b(gelu_f(acc[mi][ni][j] + be[f]));
                }
            }
        }
    }
}

// ---- GEMM2 [EXPERIMENT]: A direct-to-VGPR (off the fill-capped gload_lds path), B-only LDS.
//      256x128, BK=32, B 3-buf lead-2 (1 gload/wave/tile), A 2-slot prefetch (aA/aB, named
//      slots, 2-unrolled). Steady-state vmcnt(5) = {B(t+2), 4 A-loads(t+2)}; ledger verified.
//      LDS 24KB -> 3+ blocks/CU by LDS; 576 blocks mostly resident (little tail).
__global__ __launch_bounds__(512, 4) void moe_g2_kernel(
    const u16* __restrict__ h, const u16* __restrict__ Wt,
    const float* __restrict__ bias, const float* __restrict__ combine,
    const int* __restrict__ idxAll, const int* __restrict__ cntAll,
    const int* __restrict__ off, const int* __restrict__ table,
    const int* __restrict__ ntab, float* __restrict__ out)
{
    const int gid = blockIdx.x;
    const int ti = gid % NTILE_MAX;
    const int tn = gid / NTILE_MAX;
    if (ti >= *ntab) return;
    const int ent = table[ti];
    const int e = ent & 15, tm = ent >> 4;
    const int cnt = cntAll[e], base = off[e];
    const int* idx_e = idxAll + e * T_;
    const u16* Bsrc = Wt + (size_t)e * ((size_t)D_ * F_);

    __shared__ __align__(16) char lds[3 * 8192];   // B only: 3 bufs x 8KB

    const int tid = threadIdx.x;
    const int l = tid & 63, wid = tid >> 6;
    const int wm = (wid >> 1) * 64, wn = (wid & 1) * 64;
    const int lr = l & 15, lg = l >> 4;
    constexpr int NT = 128;   // K = 4096

    // B stage (r11 pattern: wave wid = col chunk wid, source-swizzled, linear dest)
    const int qsrc = ((l & 3) ^ ((l >> 3) & 3)) * 8;
    const u16* bP;
    {
        int cc = tn * 128 + wid * 16 + (l >> 2);
        bP = Bsrc + (size_t)cc * F_ + qsrc;
    }
    // A direct row pointers: frag mi row = wm + mi*16 + lr; k = t*32 + lg*8 (no swizzle needed)
    const u16* aRow[4];
    #pragma unroll
    for (int mi = 0; mi < 4; ++mi) {
        int hr = base + tm * 256 + wm + mi * 16 + lr;
        if (hr > HROWS_ - 1) hr = HROWS_ - 1;
        aRow[mi] = h + (size_t)hr * F_ + lg * 8;
    }

    f32x4 acc[4][4];
    #pragma unroll
    for (int mi = 0; mi < 4; ++mi)
        #pragma unroll
        for (int ni = 0; ni < 4; ++ni) acc[mi][ni] = (f32x4){0.f,0.f,0.f,0.f};

    // prologue: B0, B1 (oldest in FIFO), then 4 A(t=0) -> aA, 4 A(t=1) -> aB.
    // vmcnt(9) = {B1, 8 A loads} outstanding => B0 complete; barrier publishes it.
    bf16x8 aA[4], aB[4];
    GLOAD16(bP + 0,  lds + 0 * 8192 + wid * 1024);
    GLOAD16(bP + 32, lds + 1 * 8192 + wid * 1024);
    #pragma unroll
    for (int mi = 0; mi < 4; ++mi) aA[mi] = *(const bf16x8*)(aRow[mi]);
    #pragma unroll
    for (int mi = 0; mi < 4; ++mi) aB[mi] = *(const bf16x8*)(aRow[mi] + 32);
    asm volatile("s_waitcnt vmcnt(9)" ::: "memory");
    __builtin_amdgcn_s_barrier();

    const int koff = ((((lr >> 1) & 3) ^ lg) << 4);

    // 2-unrolled main loop; AV alternates named slots aA/aB (static indexing, rule #20).
    // Guards use runtime t; vmcnt literals fixed per branch (same as r11).
#define G2_TILE(AV, TEXPR)                                                      \
    {                                                                           \
        const int t = (TEXPR);                                                  \
        const char* Bb = lds + (t % 3) * 8192;                                  \
        bf16x8 b[4];                                                            \
        _Pragma("unroll")                                                       \
        for (int ni = 0; ni < 4; ++ni)                                          \
            b[ni] = *(const bf16x8*)(Bb + (wn + ni * 16 + lr) * 64 + koff);     \
        if (t < NT - 2)                                                         \
            GLOAD16(bP + (t + 2) * 32, lds + ((t + 2) % 3) * 8192 + wid * 1024);\
        __builtin_amdgcn_s_setprio(1);                                          \
        _Pragma("unroll")                                                       \
        for (int mi = 0; mi < 4; ++mi)                                          \
            _Pragma("unroll")                                                   \
            for (int ni = 0; ni < 4; ++ni)                                      \
                acc[mi][ni] = __builtin_amdgcn_mfma_f32_16x16x32_bf16(          \
                    AV[mi], b[ni], acc[mi][ni], 0, 0, 0);                       \
        __builtin_amdgcn_s_setprio(0);                                          \
        if (t < NT - 2) {                                                       \
            _Pragma("unroll")                                                   \
            for (int mi = 0; mi < 4; ++mi)                                      \
                AV[mi] = *(const bf16x8*)(aRow[mi] + (t + 2) * 32);             \
            asm volatile("s_waitcnt vmcnt(5)" ::: "memory");                    \
        } else if (t == NT - 2) {                                               \
            asm volatile("s_waitcnt vmcnt(0)" ::: "memory");                    \
        }                                                                       \
        if (t < NT - 1) __builtin_amdgcn_s_barrier();                           \
    }

    #pragma unroll 1
    for (int t2 = 0; t2 < NT / 2; ++t2) {
        G2_TILE(aA, 2 * t2);
        G2_TILE(aB, 2 * t2 + 1);
    }
#undef G2_TILE

    const float* be = bias + e * D_;
    #pragma unroll
    for (int mi = 0; mi < 4; ++mi) {
        #pragma unroll
        for (int j = 0; j < 4; ++j) {
            int rl = tm * 256 + wm + mi * 16 + lg * 4 + j;
            if (rl < cnt) {
                int tkn = idx_e[rl];
                float cw = combine[tkn * E_ + e];
                float* orow = out + (size_t)tkn * D_;
                #pragma unroll
                for (int ni = 0; ni < 4; ++ni) {
                    int d = tn * 128 + wn + ni * 16 + lr;
                    atomicAdd(&orow[d], cw * (acc[mi][ni][j] + be[d]));
                }
            }
        }
    }
}

__global__ void sentinel_kernel(float* __restrict__ dst) {
    if (threadIdx.x == 0) dst[0] = -12345.0f;
}

extern "C" void kernel_launch(void* const* d_in, const int* in_sizes, int n_in,
                              void* d_out, int out_size, void* d_ws, size_t ws_size,
                              hipStream_t stream)
{
    const float* x  = (const float*)d_in[0];
    const float* ew = (const float*)d_in[1];
    const float* gw = (const float*)d_in[2];
    const float* gb = (const float*)d_in[3];
    const float* w1 = (const float*)d_in[4];
    const float* b1 = (const float*)d_in[5];
    const float* w2 = (const float*)d_in[6];
    const float* b2 = (const float*)d_in[7];
    float* out = (float*)d_out;

    char* ws = (char*)d_ws;
    size_t o = 0;
    u16* w1t = (u16*)(ws + o); o += (size_t)E_ * D_ * F_ * 2;
    u16* w2t = (u16*)(ws + o); o += (size_t)E_ * F_ * D_ * 2;
    u16* xb  = (u16*)(ws + o); o += (size_t)T_ * D_ * 2;
    u16* h   = (u16*)(ws + o); o += (size_t)HROWS_ * F_ * 2;
    float* combine = (float*)(ws + o); o += (size_t)T_ * E_ * 4;
    int* idx = (int*)(ws + o); o += (size_t)E_ * T_ * 4;
    size_t zoff = o;
    int* cnt   = (int*)(ws + o); o += 128;
    int* fcnt  = (int*)(ws + o); o += 64 * E_ * 4;
    float* psum = (float*)(ws + o); o += 64 * E_ * 4;
    int* off   = (int*)(ws + o); o += 128;
    int* table = (int*)(ws + o); o += 512;
    int* ntab  = (int*)(ws + o); o += 128;
    const size_t ws_needed = o;

    if (ws_size < ws_needed) {
        (void)hipMemsetAsync(d_out, 0, (size_t)out_size * sizeof(float), stream);
        sentinel_kernel<<<1, 64, 0, stream>>>(out + (size_t)out_size - 1);
        return;
    }

    (void)hipMemsetAsync(ws + zoff, 0, ws_needed - zoff, stream);
    (void)hipMemsetAsync(d_out, 0, (size_t)out_size * sizeof(float), stream);

    cvt_T_kernel<<<dim3(F_ / 64, D_ / 64, E_), 256, 0, stream>>>(w1, w1t, D_, F_);
    cvt_T_kernel<<<dim3(D_ / 64, F_ / 64, E_), 256, 0, stream>>>(w2, w2t, F_, D_);
    gate_kernel<<<T_, 64, 0, stream>>>(x, ew, gw, gb, xb, combine, idx, cnt, fcnt, psum);
    tiletab_kernel<<<1, 64, 0, stream>>>(cnt, off, table, ntab, fcnt, psum,
                                         out + (size_t)out_size - 1);
    // gemm1: 256x128, 72x32 = 2304 blocks, 2 blocks/CU (r11 structure, gather inlined)
    moe_g1_kernel<<<NTILE_MAX * 32, 512, 0, stream>>>(
        xb, w1t, b1, idx, cnt, off, table, ntab, h);
    // gemm2: A-direct + B-staged, 72x8 = 576 blocks
    moe_g2_kernel<<<NTILE_MAX * 8, 512, 0, stream>>>(
        h, w2t, b2, combine, idx, cnt, off, table, ntab, out);
}

// Round 17
// 805.516 us; speedup vs baseline: 1.4611x; 1.4611x over previous
//
#include <hip/hip_runtime.h>
#include <math.h>

#define B_ 4
#define S_ 2048
#define D_ 1024
#define F_ 4096
#define E_ 8
#define T_ 8192
#define LBW_ 0.01f
#define HROWS_ 17408   // sum of per-expert 128-padded counts <= 16384 + 8*127
#define NTILE_MAX 72   // max total 256-row M-tiles across experts

#define BUFB 24576     // GEMM LDS buffer: A 256x32x2 (16384) + B 128x32x2 (8192)

typedef unsigned short u16;
typedef __attribute__((ext_vector_type(8))) short bf16x8;
typedef __attribute__((ext_vector_type(4))) float f32x4;

#define GLOAD16(gp, lp) __builtin_amdgcn_global_load_lds( \
    (const __attribute__((address_space(1))) void*)(gp),  \
    (__attribute__((address_space(3))) void*)(lp), 16, 0, 0)

__device__ __forceinline__ u16 f2b(float f) {
    unsigned u = __float_as_uint(f);
    u = (u + 0x7FFFu + ((u >> 16) & 1u)) >> 16;   // RNE f32 -> bf16
    return (u16)u;
}
__device__ __forceinline__ float gelu_f(float v) {
    return 0.5f * v * (1.0f + erff(v * 0.70710678118654752440f));
}

// ------- both weight transposes in one launch (r12-verified): w1->w1t (FxD), w2->w2t (DxF) ----
__global__ __launch_bounds__(256) void cvt_both_kernel(const float* __restrict__ w1,
                                                       const float* __restrict__ w2,
                                                       u16* __restrict__ w1t,
                                                       u16* __restrict__ w2t) {
    __shared__ u16 t[64][72];
    const int bid = blockIdx.x;
    const int w = bid >> 13;              // 0: w1, 1: w2
    const int r2 = bid & 8191;
    const int e = r2 >> 10, cell = r2 & 1023;
    const int R = w ? F_ : D_, C = w ? D_ : F_;
    const int bx = w ? (cell & 15) : (cell & 63);
    const int by = w ? (cell >> 4) : (cell >> 6);
    const float* s = (w ? w2 : w1) + (size_t)e * D_ * F_;
    u16* d = (w ? w2t : w1t) + (size_t)e * D_ * F_;
    const int r0 = by * 64, c0 = bx * 64;
    const int tid = threadIdx.x;
    {
        int rr = tid >> 2, cq = (tid & 3) * 16;
        #pragma unroll
        for (int j = 0; j < 16; j += 4) {
            float4 v = *(const float4*)(s + (size_t)(r0 + rr) * C + c0 + cq + j);
            t[cq + j + 0][rr] = f2b(v.x);
            t[cq + j + 1][rr] = f2b(v.y);
            t[cq + j + 2][rr] = f2b(v.z);
            t[cq + j + 3][rr] = f2b(v.w);
        }
    }
    __syncthreads();
    {
        int cr = tid >> 2, rq = (tid & 3) * 16;
        #pragma unroll
        for (int j = 0; j < 16; j += 8) {
            int4 pk; u16* pw = (u16*)&pk;
            #pragma unroll
            for (int jj = 0; jj < 8; ++jj) pw[jj] = t[cr][rq + j + jj];
            *(int4*)(d + (size_t)(c0 + cr) * R + r0 + rq + j) = pk;
        }
    }
}

// ------- gate [r11 form]: f64 logits, softmax, top-2, lists, loss partials; x->bf16 -------
__global__ __launch_bounds__(64) void gate_kernel(
    const float* __restrict__ x, const float* __restrict__ ew,
    const float* __restrict__ gw, const float* __restrict__ gb,
    u16* __restrict__ xb,
    float* __restrict__ combine, int* __restrict__ idx, int* __restrict__ cnt,
    int* __restrict__ fcnt, float* __restrict__ psum)
{
    const int t = blockIdx.x, l = threadIdx.x;
    const float* xr = x + (size_t)t * D_;
    double acc[E_];
    #pragma unroll
    for (int e = 0; e < E_; ++e) acc[e] = 0.0;
    u16 xw[16];
    #pragma unroll
    for (int kk = 0; kk < 16; kk += 4) {
        float4 xv = *(const float4*)(xr + l * 16 + kk);
        float xs[4] = {xv.x, xv.y, xv.z, xv.w};
        #pragma unroll
        for (int j = 0; j < 4; ++j) {
            xw[kk + j] = f2b(xs[j]);
            const float* gr = gw + (size_t)(l * 16 + kk + j) * E_;
            float4 g0 = *(const float4*)(gr);
            float4 g1 = *(const float4*)(gr + 4);
            acc[0] += (double)xs[j] * g0.x;  acc[1] += (double)xs[j] * g0.y;
            acc[2] += (double)xs[j] * g0.z;  acc[3] += (double)xs[j] * g0.w;
            acc[4] += (double)xs[j] * g1.x;  acc[5] += (double)xs[j] * g1.y;
            acc[6] += (double)xs[j] * g1.z;  acc[7] += (double)xs[j] * g1.w;
        }
    }
    *(int4*)(xb + (size_t)t * D_ + l * 16)     = *(int4*)(xw);
    *(int4*)(xb + (size_t)t * D_ + l * 16 + 8) = *(int4*)(xw + 8);
    #pragma unroll
    for (int e = 0; e < E_; ++e) {
        #pragma unroll
        for (int m = 32; m > 0; m >>= 1) acc[e] += __shfl_xor(acc[e], m);
    }
    if (l == 0) {
        const int b = t / S_;
        double p[E_]; double mx = -1e300;
        #pragma unroll
        for (int e = 0; e < E_; ++e) {
            p[e] = acc[e] + (double)gb[e] + (double)ew[b * E_ + e];
            mx = fmax(mx, p[e]);
        }
        double s = 0.0;
        #pragma unroll
        for (int e = 0; e < E_; ++e) { p[e] = exp(p[e] - mx); s += p[e]; }
        double inv = 1.0 / s;
        #pragma unroll
        for (int e = 0; e < E_; ++e) p[e] *= inv;
        double m1 = -1.0; int e1 = 0;
        #pragma unroll
        for (int e = 0; e < E_; ++e) if (p[e] > m1) { m1 = p[e]; e1 = e; }
        double m2 = -1.0; int e2 = 0;
        #pragma unroll
        for (int e = 0; e < E_; ++e) if (e != e1 && p[e] > m2) { m2 = p[e]; e2 = e; }
        float c1 = (float)(m1 / (m1 + m2)), c2 = (float)(m2 / (m1 + m2));
        #pragma unroll
        for (int e = 0; e < E_; ++e)
            combine[t * E_ + e] = (e == e1) ? c1 : ((e == e2) ? c2 : 0.0f);
        int q1 = atomicAdd(&cnt[e1], 1); idx[e1 * T_ + q1] = t;
        int q2 = atomicAdd(&cnt[e2], 1); idx[e2 * T_ + q2] = t;
        atomicAdd(&fcnt[(t & 63) * E_ + e1], 1);
        #pragma unroll
        for (int e = 0; e < E_; ++e) atomicAdd(&psum[(t & 63) * E_ + e], (float)p[e]);
    }
}

// ------- offsets + tile table + loss (merged) -------
__global__ void tiletab_kernel(const int* __restrict__ cnt, int* __restrict__ off,
                               int* __restrict__ table, int* __restrict__ ntab,
                               const int* __restrict__ fcnt, const float* __restrict__ psum,
                               float* __restrict__ lossdst) {
    if (threadIdx.x == 0 && blockIdx.x == 0) {
        int o = 0, k = 0;
        for (int e = 0; e < E_; ++e) {
            off[e] = o;
            int pad = ((cnt[e] + 127) >> 7) << 7;
            o += pad;
            int nt = (pad + 255) >> 8;
            for (int i = 0; i < nt; ++i) table[k++] = e | (i << 4);
        }
        off[E_] = o;
        *ntab = k;
        float loss = 0.f;
        for (int e = 0; e < E_; ++e) {
            float fs = 0.f, Ps = 0.f;
            for (int s = 0; s < 64; ++s) { fs += (float)fcnt[s * E_ + e]; Ps += psum[s * E_ + e]; }
            loss += (fs / (float)T_) * (Ps / (float)T_);
        }
        *lossdst = LBW_ * (float)E_ * loss;
    }
}

// ---- GEMM template (r11 structure): 256x128, BK=32, 3-buffer lead-2 counted vmcnt(3),
//      72KB LDS + ~60 VGPR -> 2 blocks/CU (dual fill streams = the measured optimum).
//      Source-swizzled staging (linear LDS dest, rule 21), conflict-free verified.
//      IS_G1: A rows gathered via idx (inline), out = gelu(acc+b1) -> h.
//      else:  A rows contiguous in h,          out: atomicAdd(combine*(acc+b2)).
template<int NT, int KDROW, bool IS_G1>
__global__ __launch_bounds__(512, 4) void moe_gemm_kernel(
    const u16* __restrict__ Aglob, const u16* __restrict__ Wt,
    const float* __restrict__ bias, const float* __restrict__ combine,
    const int* __restrict__ idxAll, const int* __restrict__ cntAll,
    const int* __restrict__ off, const int* __restrict__ table,
    const int* __restrict__ ntab,
    u16* __restrict__ hOut, float* __restrict__ out)
{
    const int gid = blockIdx.x;
    const int ti = gid % NTILE_MAX;
    const int tn = gid / NTILE_MAX;
    if (ti >= *ntab) return;
    const int ent = table[ti];
    const int e = ent & 15, tm = ent >> 4;
    const int cnt = cntAll[e], base = off[e];
    const int* idx_e = idxAll + e * T_;
    const u16* Bsrc = Wt + (size_t)e * ((size_t)D_ * F_);

    __shared__ __align__(16) char lds[3 * BUFB];

    const int tid = threadIdx.x;
    const int l = tid & 63, wid = tid >> 6;
    const int wm = (wid >> 1) * 64, wn = (wid & 1) * 64;   // wave tile 64x64 in 256x128
    const int lr = l & 15, lg = l >> 4;

    // stage: A 16 chunks of 16 rows (wave owns {2wid,2wid+1}); B 8 chunks (wave owns wid).
    // lane -> row 16c+(l>>2), dest slot l&3; SOURCE k-chunk (l&3)^((l>>3)&3)
    // (LDS[r][slot q] = global chunk q^((r>>1)&3); read slot lg^((lr>>1)&3); conflict-free)
    const int qsrc = ((l & 3) ^ ((l >> 3) & 3)) * 8;
    const u16* aP[2]; const u16* bP;
    #pragma unroll
    for (int i = 0; i < 2; ++i) {
        int c = 2 * wid + i;
        int r = tm * 256 + c * 16 + (l >> 2);
        if (IS_G1) {
            int tok = (r < cnt) ? idx_e[r] : idx_e[0];   // inline gather (r3 pattern)
            aP[i] = Aglob + (size_t)tok * KDROW + qsrc;
        } else {
            int hr = base + r; if (hr > HROWS_ - 1) hr = HROWS_ - 1;
            aP[i] = Aglob + (size_t)hr * KDROW + qsrc;
        }
    }
    {
        int cc = tn * 128 + wid * 16 + (l >> 2);
        bP = Bsrc + (size_t)cc * KDROW + qsrc;
    }

    f32x4 acc[4][4];
    #pragma unroll
    for (int mi = 0; mi < 4; ++mi)
        #pragma unroll
        for (int ni = 0; ni < 4; ++ni) acc[mi][ni] = (f32x4){0.f,0.f,0.f,0.f};

    auto stage = [&](int sb, int kof) {
        GLOAD16(aP[0] + kof, lds + sb + (2 * wid) * 1024);
        GLOAD16(aP[1] + kof, lds + sb + (2 * wid + 1) * 1024);
        GLOAD16(bP + kof, lds + sb + 16384 + wid * 1024);
    };

    // prologue: stage tiles 0,1; drain tile 0 only (tile 1's 3 loads stay in flight)
    stage(0, 0);
    stage(BUFB, 32);
    asm volatile("s_waitcnt vmcnt(3)" ::: "memory");
    __builtin_amdgcn_s_barrier();

    const int koff = ((((lr >> 1) & 3) ^ lg) << 4);
    int cb = 0, sb2 = 2 * BUFB, kofe = 64;
    for (int t = 0; t < NT; ++t) {
        bf16x8 a[4], b[4];
        #pragma unroll
        for (int mi = 0; mi < 4; ++mi)
            a[mi] = *(const bf16x8*)(lds + cb + (wm + mi * 16 + lr) * 64 + koff);
        #pragma unroll
        for (int ni = 0; ni < 4; ++ni)
            b[ni] = *(const bf16x8*)(lds + cb + 16384 + (wn + ni * 16 + lr) * 64 + koff);
        if (t < NT - 2) { stage(sb2, kofe); kofe += 32; }
        __builtin_amdgcn_s_setprio(1);
        #pragma unroll
        for (int mi = 0; mi < 4; ++mi)
            #pragma unroll
            for (int ni = 0; ni < 4; ++ni)
                acc[mi][ni] = __builtin_amdgcn_mfma_f32_16x16x32_bf16(a[mi], b[ni], acc[mi][ni], 0, 0, 0);
        __builtin_amdgcn_s_setprio(0);
        if (t < NT - 2)       { asm volatile("s_waitcnt vmcnt(3)" ::: "memory"); }
        else if (t == NT - 2) { asm volatile("s_waitcnt vmcnt(0)" ::: "memory"); }
        if (t < NT - 1) __builtin_amdgcn_s_barrier();
        cb += BUFB;  if (cb == 3 * BUFB)  cb = 0;
        sb2 += BUFB; if (sb2 == 3 * BUFB) sb2 = 0;
    }

    // ---- epilogue: C/D frag row = lg*4+j, col = lr ----
    if (IS_G1) {
        const float* be = bias + e * F_;
        const int pad = ((cnt + 127) >> 7) << 7;
        #pragma unroll
        for (int mi = 0; mi < 4; ++mi) {
            #pragma unroll
            for (int j = 0; j < 4; ++j) {
                int rl = tm * 256 + wm + mi * 16 + lg * 4 + j;
                if (rl < pad) {
                    size_t srow = (size_t)(base + rl) * F_;
                    #pragma unroll
                    for (int ni = 0; ni < 4; ++ni) {
                        int f = tn * 128 + wn + ni * 16 + lr;
                        hOut[srow + f] = f2b(gelu_f(acc[mi][ni][j] + be[f]));
                    }
                }
            }
        }
    } else {
        const float* be = bias + e * D_;
        #pragma unroll
        for (int mi = 0; mi < 4; ++mi) {
            #pragma unroll
            for (int j = 0; j < 4; ++j) {
                int rl = tm * 256 + wm + mi * 16 + lg * 4 + j;
                if (rl < cnt) {
                    int tkn = idx_e[rl];
                    float cw = combine[tkn * E_ + e];
                    float* orow = out + (size_t)tkn * D_;
                    #pragma unroll
                    for (int ni = 0; ni < 4; ++ni) {
                        int d = tn * 128 + wn + ni * 16 + lr;
                        atomicAdd(&orow[d], cw * (acc[mi][ni][j] + be[d]));
                    }
                }
            }
        }
    }
}

__global__ void sentinel_kernel(float* __restrict__ dst) {
    if (threadIdx.x == 0) dst[0] = -12345.0f;
}

extern "C" void kernel_launch(void* const* d_in, const int* in_sizes, int n_in,
                              void* d_out, int out_size, void* d_ws, size_t ws_size,
                              hipStream_t stream)
{
    const float* x  = (const float*)d_in[0];
    const float* ew = (const float*)d_in[1];
    const float* gw = (const float*)d_in[2];
    const float* gb = (const float*)d_in[3];
    const float* w1 = (const float*)d_in[4];
    const float* b1 = (const float*)d_in[5];
    const float* w2 = (const float*)d_in[6];
    const float* b2 = (const float*)d_in[7];
    float* out = (float*)d_out;

    char* ws = (char*)d_ws;
    size_t o = 0;
    u16* w1t = (u16*)(ws + o); o += (size_t)E_ * D_ * F_ * 2;
    u16* w2t = (u16*)(ws + o); o += (size_t)E_ * F_ * D_ * 2;
    u16* xb  = (u16*)(ws + o); o += (size_t)T_ * D_ * 2;
    u16* h   = (u16*)(ws + o); o += (size_t)HROWS_ * F_ * 2;
    float* combine = (float*)(ws + o); o += (size_t)T_ * E_ * 4;
    int* idx = (int*)(ws + o); o += (size_t)E_ * T_ * 4;
    size_t zoff = o;
    int* cnt   = (int*)(ws + o); o += 128;
    int* fcnt  = (int*)(ws + o); o += 64 * E_ * 4;
    float* psum = (float*)(ws + o); o += 64 * E_ * 4;
    int* off   = (int*)(ws + o); o += 128;
    int* table = (int*)(ws + o); o += 512;
    int* ntab  = (int*)(ws + o); o += 128;
    const size_t ws_needed = o;

    if (ws_size < ws_needed) {
        (void)hipMemsetAsync(d_out, 0, (size_t)out_size * sizeof(float), stream);
        sentinel_kernel<<<1, 64, 0, stream>>>(out + (size_t)out_size - 1);
        return;
    }

    (void)hipMemsetAsync(ws + zoff, 0, ws_needed - zoff, stream);
    (void)hipMemsetAsync(d_out, 0, (size_t)out_size * sizeof(float), stream);

    cvt_both_kernel<<<16384, 256, 0, stream>>>(w1, w2, w1t, w2t);
    gate_kernel<<<T_, 64, 0, stream>>>(x, ew, gw, gb, xb, combine, idx, cnt, fcnt, psum);
    tiletab_kernel<<<1, 64, 0, stream>>>(cnt, off, table, ntab, fcnt, psum,
                                         out + (size_t)out_size - 1);
    // gemm1: inline-gather A from xb, K=1024; 72x32 = 2304 blocks, 2 blocks/CU
    moe_gemm_kernel<32, 1024, true><<<NTILE_MAX * 32, 512, 0, stream>>>(
        xb, w1t, b1, nullptr, idx, cnt, off, table, ntab, h, nullptr);
    // gemm2: r11 verbatim, K=4096; 72x8 = 576 blocks, 2 blocks/CU
    moe_gemm_kernel<128, 4096, false><<<NTILE_MAX * 8, 512, 0, stream>>>(
        h, w2t, b2, combine, idx, cnt, off, table, ntab, nullptr, out);
}

// Round 18
// 692.450 us; speedup vs baseline: 1.6997x; 1.1633x over previous
//
#include <hip/hip_runtime.h>
#include <math.h>

#define B_ 4
#define S_ 2048
#define D_ 1024
#define F_ 4096
#define E_ 8
#define T_ 8192
#define LBW_ 0.01f
#define HROWS_ 17408   // sum of per-expert 128-padded counts <= 16384 + 8*127
#define NTILE_MAX 72   // max total 256-row M-tiles across experts

#define BUFB 24576     // GEMM LDS buffer: A 256x32x2 (16384) + B 128x32x2 (8192)

typedef unsigned short u16;
typedef __attribute__((ext_vector_type(8))) short bf16x8;
typedef __attribute__((ext_vector_type(4))) float f32x4;

#define GLOAD16(gp, lp) __builtin_amdgcn_global_load_lds( \
    (const __attribute__((address_space(1))) void*)(gp),  \
    (__attribute__((address_space(3))) void*)(lp), 16, 0, 0)

__device__ __forceinline__ u16 f2b(float f) {
    unsigned u = __float_as_uint(f);
    u = (u + 0x7FFFu + ((u >> 16) & 1u)) >> 16;   // RNE f32 -> bf16
    return (u16)u;
}
__device__ __forceinline__ float gelu_f(float v) {
    return 0.5f * v * (1.0f + erff(v * 0.70710678118654752440f));
}

// ------- both weight transposes in one launch: w1->w1t (FxD), w2->w2t (DxF) -------
__global__ __launch_bounds__(256) void cvt_both_kernel(const float* __restrict__ w1,
                                                       const float* __restrict__ w2,
                                                       u16* __restrict__ w1t,
                                                       u16* __restrict__ w2t) {
    __shared__ u16 t[64][72];
    const int bid = blockIdx.x;
    const int w = bid >> 13;              // 0: w1, 1: w2
    const int r2 = bid & 8191;
    const int e = r2 >> 10, cell = r2 & 1023;
    const int R = w ? F_ : D_, C = w ? D_ : F_;
    const int bx = w ? (cell & 15) : (cell & 63);
    const int by = w ? (cell >> 4) : (cell >> 6);
    const float* s = (w ? w2 : w1) + (size_t)e * D_ * F_;
    u16* d = (w ? w2t : w1t) + (size_t)e * D_ * F_;
    const int r0 = by * 64, c0 = bx * 64;
    const int tid = threadIdx.x;
    {
        int rr = tid >> 2, cq = (tid & 3) * 16;
        #pragma unroll
        for (int j = 0; j < 16; j += 4) {
            float4 v = *(const float4*)(s + (size_t)(r0 + rr) * C + c0 + cq + j);
            t[cq + j + 0][rr] = f2b(v.x);
            t[cq + j + 1][rr] = f2b(v.y);
            t[cq + j + 2][rr] = f2b(v.z);
            t[cq + j + 3][rr] = f2b(v.w);
        }
    }
    __syncthreads();
    {
        int cr = tid >> 2, rq = (tid & 3) * 16;
        #pragma unroll
        for (int j = 0; j < 16; j += 8) {
            int4 pk; u16* pw = (u16*)&pk;
            #pragma unroll
            for (int jj = 0; jj < 8; ++jj) pw[jj] = t[cr][rq + j + jj];
            *(int4*)(d + (size_t)(c0 + cr) * R + r0 + rq + j) = pk;
        }
    }
}

// ------- gate: f64 logits, softmax, top-2; SPREAD counters only (no hot-8 atomics) -------
__global__ __launch_bounds__(64) void gate_kernel(
    const float* __restrict__ x, const float* __restrict__ ew,
    const float* __restrict__ gw, const float* __restrict__ gb,
    u16* __restrict__ xb,
    float* __restrict__ combine, int* __restrict__ choice, int* __restrict__ scnt,
    int* __restrict__ fcnt, float* __restrict__ psum)
{
    const int t = blockIdx.x, l = threadIdx.x;
    const float* xr = x + (size_t)t * D_;
    double acc[E_];
    #pragma unroll
    for (int e = 0; e < E_; ++e) acc[e] = 0.0;
    u16 xw[16];
    #pragma unroll
    for (int kk = 0; kk < 16; kk += 4) {
        float4 xv = *(const float4*)(xr + l * 16 + kk);
        float xs[4] = {xv.x, xv.y, xv.z, xv.w};
        #pragma unroll
        for (int j = 0; j < 4; ++j) {
            xw[kk + j] = f2b(xs[j]);
            const float* gr = gw + (size_t)(l * 16 + kk + j) * E_;
            float4 g0 = *(const float4*)(gr);
            float4 g1 = *(const float4*)(gr + 4);
            acc[0] += (double)xs[j] * g0.x;  acc[1] += (double)xs[j] * g0.y;
            acc[2] += (double)xs[j] * g0.z;  acc[3] += (double)xs[j] * g0.w;
            acc[4] += (double)xs[j] * g1.x;  acc[5] += (double)xs[j] * g1.y;
            acc[6] += (double)xs[j] * g1.z;  acc[7] += (double)xs[j] * g1.w;
        }
    }
    *(int4*)(xb + (size_t)t * D_ + l * 16)     = *(int4*)(xw);
    *(int4*)(xb + (size_t)t * D_ + l * 16 + 8) = *(int4*)(xw + 8);
    #pragma unroll
    for (int e = 0; e < E_; ++e) {
        #pragma unroll
        for (int m = 32; m > 0; m >>= 1) acc[e] += __shfl_xor(acc[e], m);
    }
    if (l == 0) {
        const int b = t / S_;
        double p[E_]; double mx = -1e300;
        #pragma unroll
        for (int e = 0; e < E_; ++e) {
            p[e] = acc[e] + (double)gb[e] + (double)ew[b * E_ + e];
            mx = fmax(mx, p[e]);
        }
        double s = 0.0;
        #pragma unroll
        for (int e = 0; e < E_; ++e) { p[e] = exp(p[e] - mx); s += p[e]; }
        double inv = 1.0 / s;
        #pragma unroll
        for (int e = 0; e < E_; ++e) p[e] *= inv;
        double m1 = -1.0; int e1 = 0;
        #pragma unroll
        for (int e = 0; e < E_; ++e) if (p[e] > m1) { m1 = p[e]; e1 = e; }
        double m2 = -1.0; int e2 = 0;
        #pragma unroll
        for (int e = 0; e < E_; ++e) if (e != e1 && p[e] > m2) { m2 = p[e]; e2 = e; }
        float c1 = (float)(m1 / (m1 + m2)), c2 = (float)(m2 / (m1 + m2));
        #pragma unroll
        for (int e = 0; e < E_; ++e)
            combine[t * E_ + e] = (e == e1) ? c1 : ((e == e2) ? c2 : 0.0f);
        const int bu = t & 63;
        choice[t] = e1 | (e2 << 4);
        atomicAdd(&scnt[bu * E_ + e1], 1);     // 512-way spread: ~32 hits/address
        atomicAdd(&scnt[bu * E_ + e2], 1);
        atomicAdd(&fcnt[bu * E_ + e1], 1);     // top-1 count (loss)
        #pragma unroll
        for (int e = 0; e < E_; ++e) atomicAdd(&psum[bu * E_ + e], (float)p[e]);
    }
}

// ------- offsets + tile table + loss + bucket prefixes (serial, one thread) -------
__global__ void tiletab_kernel(const int* __restrict__ scnt, int* __restrict__ cnt,
                               int* __restrict__ off, int* __restrict__ boff,
                               int* __restrict__ table, int* __restrict__ ntab,
                               const int* __restrict__ fcnt, const float* __restrict__ psum,
                               float* __restrict__ lossdst) {
    if (threadIdx.x == 0 && blockIdx.x == 0) {
        // per-expert totals + per-bucket prefix within each expert's list
        for (int e = 0; e < E_; ++e) {
            int c = 0;
            for (int b = 0; b < 64; ++b) { boff[b * E_ + e] = c; c += scnt[b * E_ + e]; }
            cnt[e] = c;
        }
        int o = 0, k = 0;
        for (int e = 0; e < E_; ++e) {
            off[e] = o;
            int pad = ((cnt[e] + 127) >> 7) << 7;
            o += pad;
            int nt = (pad + 255) >> 8;
            for (int i = 0; i < nt; ++i) table[k++] = e | (i << 4);
        }
        off[E_] = o;
        *ntab = k;
        float loss = 0.f;
        for (int e = 0; e < E_; ++e) {
            float fs = 0.f, Ps = 0.f;
            for (int s = 0; s < 64; ++s) { fs += (float)fcnt[s * E_ + e]; Ps += psum[s * E_ + e]; }
            loss += (fs / (float)T_) * (Ps / (float)T_);
        }
        *lossdst = LBW_ * (float)E_ * loss;
    }
}

// ------- scatter: write idx via spread sub-position counters (~32 hits/address) -------
__global__ __launch_bounds__(256) void scatter_kernel(
    const int* __restrict__ choice, const int* __restrict__ boff,
    int* __restrict__ spos, int* __restrict__ idx)
{
    const int t = blockIdx.x * 256 + threadIdx.x;
    const int ch = choice[t];
    const int e1 = ch & 15, e2 = ch >> 4;
    const int bu = t & 63;
    int r1 = atomicAdd(&spos[bu * E_ + e1], 1);
    idx[e1 * T_ + boff[bu * E_ + e1] + r1] = t;
    int r2 = atomicAdd(&spos[bu * E_ + e2], 1);
    idx[e2 * T_ + boff[bu * E_ + e2] + r2] = t;
}

// ---- GEMM template (r11 structure, FROZEN): 256x128, BK=32, 3-buffer lead-2 vmcnt(3),
//      72KB LDS + ~60 VGPR -> 2 blocks/CU. Source-swizzled staging, conflict-free verified.
template<int NT, int KDROW, bool IS_G1>
__global__ __launch_bounds__(512, 4) void moe_gemm_kernel(
    const u16* __restrict__ Aglob, const u16* __restrict__ Wt,
    const float* __restrict__ bias, const float* __restrict__ combine,
    const int* __restrict__ idxAll, const int* __restrict__ cntAll,
    const int* __restrict__ off, const int* __restrict__ table,
    const int* __restrict__ ntab,
    u16* __restrict__ hOut, float* __restrict__ out)
{
    const int gid = blockIdx.x;
    const int ti = gid % NTILE_MAX;
    const int tn = gid / NTILE_MAX;
    if (ti >= *ntab) return;
    const int ent = table[ti];
    const int e = ent & 15, tm = ent >> 4;
    const int cnt = cntAll[e], base = off[e];
    const int* idx_e = idxAll + e * T_;
    const u16* Bsrc = Wt + (size_t)e * ((size_t)D_ * F_);

    __shared__ __align__(16) char lds[3 * BUFB];

    const int tid = threadIdx.x;
    const int l = tid & 63, wid = tid >> 6;
    const int wm = (wid >> 1) * 64, wn = (wid & 1) * 64;   // wave tile 64x64 in 256x128
    const int lr = l & 15, lg = l >> 4;

    const int qsrc = ((l & 3) ^ ((l >> 3) & 3)) * 8;
    const u16* aP[2]; const u16* bP;
    #pragma unroll
    for (int i = 0; i < 2; ++i) {
        int c = 2 * wid + i;
        int r = tm * 256 + c * 16 + (l >> 2);
        if (IS_G1) {
            int tok = (r < cnt) ? idx_e[r] : idx_e[0];   // inline gather
            aP[i] = Aglob + (size_t)tok * KDROW + qsrc;
        } else {
            int hr = base + r; if (hr > HROWS_ - 1) hr = HROWS_ - 1;
            aP[i] = Aglob + (size_t)hr * KDROW + qsrc;
        }
    }
    {
        int cc = tn * 128 + wid * 16 + (l >> 2);
        bP = Bsrc + (size_t)cc * KDROW + qsrc;
    }

    f32x4 acc[4][4];
    #pragma unroll
    for (int mi = 0; mi < 4; ++mi)
        #pragma unroll
        for (int ni = 0; ni < 4; ++ni) acc[mi][ni] = (f32x4){0.f,0.f,0.f,0.f};

    auto stage = [&](int sb, int kof) {
        GLOAD16(aP[0] + kof, lds + sb + (2 * wid) * 1024);
        GLOAD16(aP[1] + kof, lds + sb + (2 * wid + 1) * 1024);
        GLOAD16(bP + kof, lds + sb + 16384 + wid * 1024);
    };

    stage(0, 0);
    stage(BUFB, 32);
    asm volatile("s_waitcnt vmcnt(3)" ::: "memory");
    __builtin_amdgcn_s_barrier();

    const int koff = ((((lr >> 1) & 3) ^ lg) << 4);
    int cb = 0, sb2 = 2 * BUFB, kofe = 64;
    for (int t = 0; t < NT; ++t) {
        bf16x8 a[4], b[4];
        #pragma unroll
        for (int mi = 0; mi < 4; ++mi)
            a[mi] = *(const bf16x8*)(lds + cb + (wm + mi * 16 + lr) * 64 + koff);
        #pragma unroll
        for (int ni = 0; ni < 4; ++ni)
            b[ni] = *(const bf16x8*)(lds + cb + 16384 + (wn + ni * 16 + lr) * 64 + koff);
        if (t < NT - 2) { stage(sb2, kofe); kofe += 32; }
        __builtin_amdgcn_s_setprio(1);
        #pragma unroll
        for (int mi = 0; mi < 4; ++mi)
            #pragma unroll
            for (int ni = 0; ni < 4; ++ni)
                acc[mi][ni] = __builtin_amdgcn_mfma_f32_16x16x32_bf16(a[mi], b[ni], acc[mi][ni], 0, 0, 0);
        __builtin_amdgcn_s_setprio(0);
        if (t < NT - 2)       { asm volatile("s_waitcnt vmcnt(3)" ::: "memory"); }
        else if (t == NT - 2) { asm volatile("s_waitcnt vmcnt(0)" ::: "memory"); }
        if (t < NT - 1) __builtin_amdgcn_s_barrier();
        cb += BUFB;  if (cb == 3 * BUFB)  cb = 0;
        sb2 += BUFB; if (sb2 == 3 * BUFB) sb2 = 0;
    }

    if (IS_G1) {
        const float* be = bias + e * F_;
        const int pad = ((cnt + 127) >> 7) << 7;
        #pragma unroll
        for (int mi = 0; mi < 4; ++mi) {
            #pragma unroll
            for (int j = 0; j < 4; ++j) {
                int rl = tm * 256 + wm + mi * 16 + lg * 4 + j;
                if (rl < pad) {
                    size_t srow = (size_t)(base + rl) * F_;
                    #pragma unroll
                    for (int ni = 0; ni < 4; ++ni) {
                        int f = tn * 128 + wn + ni * 16 + lr;
                        hOut[srow + f] = f2b(gelu_f(acc[mi][ni][j] + be[f]));
                    }
                }
            }
        }
    } else {
        const float* be = bias + e * D_;
        #pragma unroll
        for (int mi = 0; mi < 4; ++mi) {
            #pragma unroll
            for (int j = 0; j < 4; ++j) {
                int rl = tm * 256 + wm + mi * 16 + lg * 4 + j;
                if (rl < cnt) {
                    int tkn = idx_e[rl];
                    float cw = combine[tkn * E_ + e];
                    float* orow = out + (size_t)tkn * D_;
                    #pragma unroll
                    for (int ni = 0; ni < 4; ++ni) {
                        int d = tn * 128 + wn + ni * 16 + lr;
                        atomicAdd(&orow[d], cw * (acc[mi][ni][j] + be[d]));
                    }
                }
            }
        }
    }
}

__global__ void sentinel_kernel(float* __restrict__ dst) {
    if (threadIdx.x == 0) dst[0] = -12345.0f;
}

extern "C" void kernel_launch(void* const* d_in, const int* in_sizes, int n_in,
                              void* d_out, int out_size, void* d_ws, size_t ws_size,
                              hipStream_t stream)
{
    const float* x  = (const float*)d_in[0];
    const float* ew = (const float*)d_in[1];
    const float* gw = (const float*)d_in[2];
    const float* gb = (const float*)d_in[3];
    const float* w1 = (const float*)d_in[4];
    const float* b1 = (const float*)d_in[5];
    const float* w2 = (const float*)d_in[6];
    const float* b2 = (const float*)d_in[7];
    float* out = (float*)d_out;

    char* ws = (char*)d_ws;
    size_t o = 0;
    u16* w1t = (u16*)(ws + o); o += (size_t)E_ * D_ * F_ * 2;
    u16* w2t = (u16*)(ws + o); o += (size_t)E_ * F_ * D_ * 2;
    u16* xb  = (u16*)(ws + o); o += (size_t)T_ * D_ * 2;
    u16* h   = (u16*)(ws + o); o += (size_t)HROWS_ * F_ * 2;
    float* combine = (float*)(ws + o); o += (size_t)T_ * E_ * 4;
    int* idx    = (int*)(ws + o); o += (size_t)E_ * T_ * 4;
    int* choice = (int*)(ws + o); o += (size_t)T_ * 4;
    size_t zoff = o;
    int* scnt  = (int*)(ws + o); o += 64 * E_ * 4;
    int* spos  = (int*)(ws + o); o += 64 * E_ * 4;
    int* fcnt  = (int*)(ws + o); o += 64 * E_ * 4;
    float* psum = (float*)(ws + o); o += 64 * E_ * 4;
    int* cnt   = (int*)(ws + o); o += 128;
    int* off   = (int*)(ws + o); o += 128;
    int* boff  = (int*)(ws + o); o += 64 * E_ * 4;
    int* table = (int*)(ws + o); o += 512;
    int* ntab  = (int*)(ws + o); o += 128;
    const size_t ws_needed = o;

    if (ws_size < ws_needed) {
        (void)hipMemsetAsync(d_out, 0, (size_t)out_size * sizeof(float), stream);
        sentinel_kernel<<<1, 64, 0, stream>>>(out + (size_t)out_size - 1);
        return;
    }

    (void)hipMemsetAsync(ws + zoff, 0, ws_needed - zoff, stream);
    (void)hipMemsetAsync(d_out, 0, (size_t)out_size * sizeof(float), stream);

    cvt_both_kernel<<<16384, 256, 0, stream>>>(w1, w2, w1t, w2t);
    gate_kernel<<<T_, 64, 0, stream>>>(x, ew, gw, gb, xb, combine, choice, scnt, fcnt, psum);
    tiletab_kernel<<<1, 64, 0, stream>>>(scnt, cnt, off, boff, table, ntab, fcnt, psum,
                                         out + (size_t)out_size - 1);
    scatter_kernel<<<T_ / 256, 256, 0, stream>>>(choice, boff, spos, idx);
    // gemm1: inline-gather A from xb, K=1024; 72x32 = 2304 blocks, 2 blocks/CU
    moe_gemm_kernel<32, 1024, true><<<NTILE_MAX * 32, 512, 0, stream>>>(
        xb, w1t, b1, nullptr, idx, cnt, off, table, ntab, h, nullptr);
    // gemm2: K=4096; 72x8 = 576 blocks, 2 blocks/CU (frozen r11 best)
    moe_gemm_kernel<128, 4096, false><<<NTILE_MAX * 8, 512, 0, stream>>>(
        h, w2t, b2, combine, idx, cnt, off, table, ntab, nullptr, out);
}